// Round 3
// baseline (303.824 us; speedup 1.0000x reference)
//
#include <hip/hip_runtime.h>
#include <hip/hip_bf16.h>

// GraphSAGE 2-layer forward on MI355X — round 3.
// bf16 data path + MFMA GEMM (no LDS), CSR mean-aggregation with shfl-broadcast
// neighbor indices and 8-deep gather pipelining. CSR fill uses atomicExch so
// scattered 4B stores merge in L2 instead of write-through to HBM.

#define BLK 256

typedef __attribute__((ext_vector_type(8))) short short8;
typedef __attribute__((ext_vector_type(4))) float f32x4;

__device__ inline unsigned short f2bf(float f) {
    unsigned int u = __builtin_bit_cast(unsigned int, f);
    u += 0x7fffu + ((u >> 16) & 1u);  // RNE (inputs finite)
    return (unsigned short)(u >> 16);
}
__device__ inline float bf2f(unsigned short h) {
    return __builtin_bit_cast(float, ((unsigned int)h) << 16);
}

// ---------------- CSR build ----------------

__global__ __launch_bounds__(BLK) void deg_count_kernel(const int* __restrict__ dst,
                                                        int E, int* __restrict__ deg) {
    int e = blockIdx.x * BLK + threadIdx.x;
    if (e < E) atomicAdd(&deg[dst[e]], 1);
}

__global__ __launch_bounds__(BLK) void partial_sum_kernel(const int* __restrict__ deg,
                                                          int n, int* __restrict__ partials) {
    __shared__ int s[BLK];
    int t = threadIdx.x;
    int idx = blockIdx.x * BLK + t;
    s[t] = (idx < n) ? deg[idx] : 0;
    __syncthreads();
    for (int o = BLK / 2; o > 0; o >>= 1) {
        if (t < o) s[t] += s[t + o];
        __syncthreads();
    }
    if (t == 0) partials[blockIdx.x] = s[0];
}

__global__ __launch_bounds__(BLK) void scan_partials_kernel(int* __restrict__ partials, int n) {
    __shared__ int s[BLK];
    int t = threadIdx.x;
    int v = (t < n) ? partials[t] : 0;
    s[t] = v;
    __syncthreads();
    int sum = v;
    for (int o = 1; o < BLK; o <<= 1) {
        int other = (t >= o) ? s[t - o] : 0;
        __syncthreads();
        sum += other;
        s[t] = sum;
        __syncthreads();
    }
    if (t < n) partials[t] = sum - v;  // exclusive
}

__global__ __launch_bounds__(BLK) void chunk_scan_kernel(const int* __restrict__ deg,
                                                         const int* __restrict__ partials,
                                                         int n, int* __restrict__ row_start) {
    __shared__ int s[BLK];
    int t = threadIdx.x;
    int idx = blockIdx.x * BLK + t;
    int v = (idx < n) ? deg[idx] : 0;
    s[t] = v;
    __syncthreads();
    int sum = v;
    for (int o = 1; o < BLK; o <<= 1) {
        int other = (t >= o) ? s[t - o] : 0;
        __syncthreads();
        sum += other;
        s[t] = sum;
        __syncthreads();
    }
    if (idx < n) row_start[idx] = (sum - v) + partials[blockIdx.x];
}

__global__ __launch_bounds__(BLK) void fill_kernel(const int* __restrict__ src,
                                                   const int* __restrict__ dst, int E,
                                                   const int* __restrict__ row_start,
                                                   int* __restrict__ cursor,
                                                   int* __restrict__ csr_src) {
    int e = blockIdx.x * BLK + threadIdx.x;
    if (e >= E) return;
    int d = dst[e];
    int pos = atomicAdd(&cursor[d], 1);
    // atomicExch: executed in TCC/L2, line allocates in cache -> no partial-line
    // write-through to HBM (plain 4B scatter stores showed 55MB WRITE_SIZE).
    atomicExch(&csr_src[row_start[d] + pos], src[e]);
}

// ---------------- conversions / weight packing ----------------

__global__ __launch_bounds__(BLK) void f32_to_bf16_kernel(const float* __restrict__ in,
                                                          unsigned short* __restrict__ out,
                                                          int nquad) {
    int i = blockIdx.x * BLK + threadIdx.x;
    if (i >= nquad) return;
    float4 v = ((const float4*)in)[i];
    ushort4 o;
    o.x = f2bf(v.x); o.y = f2bf(v.y); o.z = f2bf(v.z); o.w = f2bf(v.w);
    ((ushort4*)out)[i] = o;
}

// All four W [K][Ncol] f32 -> MFMA B-fragment bf16 packs in one dispatch.
// P[((kb*(Ncol/16)+n16)*64 + lane)*8 + j] = W[kb*32 + (lane>>4)*8 + j][n16*16 + (lane&15)]
__global__ __launch_bounds__(BLK) void pack_all_w_kernel(const float* __restrict__ W1l,
                                                         const float* __restrict__ W1r,
                                                         const float* __restrict__ W2l,
                                                         const float* __restrict__ W2r,
                                                         unsigned short* __restrict__ P1l,
                                                         unsigned short* __restrict__ P1r,
                                                         unsigned short* __restrict__ P2l,
                                                         unsigned short* __restrict__ P2r) {
    int t = blockIdx.x * BLK + threadIdx.x;
    const float* W;
    unsigned short* P;
    int Ncol, local;
    if (t < 16384)      { W = W1l; P = P1l; Ncol = 128; local = t; }
    else if (t < 32768) { W = W1r; P = P1r; Ncol = 128; local = t - 16384; }
    else if (t < 40960) { W = W2l; P = P2l; Ncol = 64;  local = t - 32768; }
    else if (t < 49152) { W = W2r; P = P2r; Ncol = 64;  local = t - 40960; }
    else return;
    int j = local & 7;
    int lane = (local >> 3) & 63;
    int rest = local >> 9;
    int nt = Ncol >> 4;
    int n16 = rest % nt, kb = rest / nt;
    int k = kb * 32 + (lane >> 4) * 8 + j;
    int c = n16 * 16 + (lane & 15);
    P[local] = f2bf(W[(size_t)k * Ncol + c]);
}

// ---------------- mean aggregation (bf16): one wave per node ----------------
// Neighbor indices loaded 64-wide + shfl-broadcast; 8 row-gathers in flight.

__global__ __launch_bounds__(BLK) void agg_bf16_kernel(const unsigned short* __restrict__ feat,
                                                       const int* __restrict__ row_start,
                                                       const int* __restrict__ deg,
                                                       const int* __restrict__ csr_src,
                                                       unsigned short* __restrict__ out,
                                                       int n_nodes) {
    int gid = blockIdx.x * (BLK / 64) + (threadIdx.x >> 6);
    int lane = threadIdx.x & 63;
    if (gid >= n_nodes) return;
    int start = row_start[gid];
    int cnt = deg[gid];
    const unsigned int* fp = (const unsigned int*)feat;  // 2 bf16/uint, 64 uints/row
    float ax[8], ay[8];
#pragma unroll
    for (int j = 0; j < 8; j++) { ax[j] = 0.f; ay[j] = 0.f; }

    for (int base = 0; base < cnt; base += 64) {
        int rem = cnt - base;
        int m = rem < 64 ? rem : 64;
        int idx = csr_src[start + base + (lane < m ? lane : m - 1)];
        int e = 0;
        for (; e + 8 <= m; e += 8) {
            unsigned int v[8];
#pragma unroll
            for (int j = 0; j < 8; j++) {
                int s = __shfl(idx, e + j);
                v[j] = fp[(size_t)s * 64 + lane];
            }
#pragma unroll
            for (int j = 0; j < 8; j++) {
                ax[j] += bf2f((unsigned short)v[j]);
                ay[j] += bf2f((unsigned short)(v[j] >> 16));
            }
        }
        for (; e < m; ++e) {
            int s = __shfl(idx, e);
            unsigned int v = fp[(size_t)s * 64 + lane];
            ax[0] += bf2f((unsigned short)v);
            ay[0] += bf2f((unsigned short)(v >> 16));
        }
    }
    float sx = ((ax[0] + ax[1]) + (ax[2] + ax[3])) + ((ax[4] + ax[5]) + (ax[6] + ax[7]));
    float sy = ((ay[0] + ay[1]) + (ay[2] + ay[3])) + ((ay[4] + ay[5]) + (ay[6] + ay[7]));
    float inv = 1.0f / fmaxf((float)cnt, 1.0f);
    unsigned int packed = (unsigned int)f2bf(sx * inv) | ((unsigned int)f2bf(sy * inv) << 16);
    ((unsigned int*)out)[(size_t)gid * 64 + lane] = packed;
}

// ---------------- MFMA dual GEMM: out = A1@Wl + A2@Wr + bias ----------------

template <int NCOL, bool RELU, bool OUT_BF16>
__global__ __launch_bounds__(BLK) void gemm_mfma_kernel(const unsigned short* __restrict__ A1,
                                                        const unsigned short* __restrict__ A2,
                                                        const unsigned short* __restrict__ Pl,
                                                        const unsigned short* __restrict__ Pr,
                                                        const float* __restrict__ bias,
                                                        void* __restrict__ outp, int M) {
    constexpr int NT = NCOL / 16;
    const int wave = threadIdx.x >> 6, lane = threadIdx.x & 63;
    const int r0 = blockIdx.x * 128 + wave * 32;
    const int arow = lane & 15, kgrp = lane >> 4;

    f32x4 acc[2][NT];
#pragma unroll
    for (int h = 0; h < 2; h++)
#pragma unroll
        for (int n = 0; n < NT; n++) acc[h][n] = (f32x4){0.f, 0.f, 0.f, 0.f};

    const int ra = min(r0 + arow, M - 1);
    const int rb = min(r0 + 16 + arow, M - 1);

#pragma unroll
    for (int mat = 0; mat < 2; ++mat) {
        const unsigned short* A = mat ? A2 : A1;
        const unsigned short* P = mat ? Pr : Pl;
        const unsigned short* Aa = A + (size_t)ra * 128 + kgrp * 8;
        const unsigned short* Ab = A + (size_t)rb * 128 + kgrp * 8;
#pragma unroll
        for (int kb = 0; kb < 4; ++kb) {
            short8 afa = *(const short8*)(Aa + kb * 32);
            short8 afb = *(const short8*)(Ab + kb * 32);
            const unsigned short* Pk = P + (size_t)kb * NT * 512 + lane * 8;
#pragma unroll
            for (int n = 0; n < NT; ++n) {
                short8 wf = *(const short8*)(Pk + n * 512);
                acc[0][n] = __builtin_amdgcn_mfma_f32_16x16x32_bf16(afa, wf, acc[0][n], 0, 0, 0);
                acc[1][n] = __builtin_amdgcn_mfma_f32_16x16x32_bf16(afb, wf, acc[1][n], 0, 0, 0);
            }
        }
    }

    // D layout: col = lane&15, row = (lane>>4)*4 + i
#pragma unroll
    for (int n = 0; n < NT; ++n) {
        int col = n * 16 + arow;
        float bv = bias[col];
#pragma unroll
        for (int h = 0; h < 2; ++h) {
#pragma unroll
            for (int i = 0; i < 4; ++i) {
                int row = r0 + h * 16 + kgrp * 4 + i;
                if (row < M) {
                    float v = acc[h][n][i] + bv;
                    if (RELU) v = fmaxf(v, 0.f);
                    if (OUT_BF16)
                        ((unsigned short*)outp)[(size_t)row * NCOL + col] = f2bf(v);
                    else
                        ((float*)outp)[(size_t)row * NCOL + col] = v;
                }
            }
        }
    }
}

// ---------------- launch ----------------

extern "C" void kernel_launch(void* const* d_in, const int* in_sizes, int n_in,
                              void* d_out, int out_size, void* d_ws, size_t ws_size,
                              hipStream_t stream) {
    const float* x   = (const float*)d_in[0];
    const int*   ei  = (const int*)d_in[1];
    const float* W1l = (const float*)d_in[2];
    const float* W1r = (const float*)d_in[3];
    const float* b1  = (const float*)d_in[4];
    const float* W2l = (const float*)d_in[5];
    const float* W2r = (const float*)d_in[6];
    const float* b2  = (const float*)d_in[7];
    float* out = (float*)d_out;

    const int N = in_sizes[0] / 128;  // 50000
    const int E = in_sizes[1] / 2;    // 800000
    const int* src = ei;
    const int* dst = ei + E;

    char* ws = (char*)d_ws;
    size_t off = 0;
    auto carve = [&](size_t bytes) {
        void* p = ws + off;
        off += (bytes + 255) & ~(size_t)255;
        return p;
    };
    int* deg       = (int*)carve((size_t)2 * N * 4);  // deg + cursor, one memset
    int* cursor    = deg + N;
    int* row_start = (int*)carve((size_t)N * 4);
    int* partials  = (int*)carve(256 * 4);
    int* csr_src   = (int*)carve((size_t)E * 4);
    unsigned short* xb   = (unsigned short*)carve((size_t)N * 128 * 2);
    unsigned short* aggb = (unsigned short*)carve((size_t)N * 128 * 2);
    unsigned short* hb   = (unsigned short*)carve((size_t)N * 128 * 2);
    unsigned short* P1l  = (unsigned short*)carve(128 * 128 * 2);
    unsigned short* P1r  = (unsigned short*)carve(128 * 128 * 2);
    unsigned short* P2l  = (unsigned short*)carve(128 * 64 * 2);
    unsigned short* P2r  = (unsigned short*)carve(128 * 64 * 2);

    hipMemsetAsync(deg, 0, (size_t)2 * N * 4, stream);

    const int nquad = N * 128 / 4;
    f32_to_bf16_kernel<<<(nquad + BLK - 1) / BLK, BLK, 0, stream>>>(x, xb, nquad);
    pack_all_w_kernel<<<192, BLK, 0, stream>>>(W1l, W1r, W2l, W2r, P1l, P1r, P2l, P2r);

    const int nchunk = (N + BLK - 1) / BLK;  // 196 (<=256)
    deg_count_kernel<<<(E + BLK - 1) / BLK, BLK, 0, stream>>>(dst, E, deg);
    partial_sum_kernel<<<nchunk, BLK, 0, stream>>>(deg, N, partials);
    scan_partials_kernel<<<1, BLK, 0, stream>>>(partials, nchunk);
    chunk_scan_kernel<<<nchunk, BLK, 0, stream>>>(deg, partials, N, row_start);
    fill_kernel<<<(E + BLK - 1) / BLK, BLK, 0, stream>>>(src, dst, E, row_start, cursor, csr_src);

    const int aggGrid = (N + 3) / 4;
    const int gemmGrid = (N + 127) / 128;

    // layer 1: h = relu(agg(x)@W1l + b1 + x@W1r)   (bf16)
    agg_bf16_kernel<<<aggGrid, BLK, 0, stream>>>(xb, row_start, deg, csr_src, aggb, N);
    gemm_mfma_kernel<128, true, true><<<gemmGrid, BLK, 0, stream>>>(aggb, xb, P1l, P1r, b1, hb, N);
    // layer 2: out = agg(h)@W2l + b2 + h@W2r       (f32)
    agg_bf16_kernel<<<aggGrid, BLK, 0, stream>>>(hb, row_start, deg, csr_src, aggb, N);
    gemm_mfma_kernel<64, false, false><<<gemmGrid, BLK, 0, stream>>>(aggb, hb, P2l, P2r, b2, out, N);
}